// Round 5
// baseline (401.509 us; speedup 1.0000x reference)
//
#include <hip/hip_runtime.h>
#include <hip/hip_cooperative_groups.h>

namespace cg = cooperative_groups;

#define N_NODES 50000
#define NBUCK 782        // ceil(N_NODES / 64) -- 64 dst-nodes per bucket
#define BCAP 2048        // slots per bucket (mean fill 1024 + pad <=448)
#define BSHIFT 11

typedef __attribute__((ext_vector_type(8))) short short8;
typedef __attribute__((ext_vector_type(4))) float floatx4;
typedef __attribute__((ext_vector_type(2))) float floatx2;
typedef __attribute__((ext_vector_type(2))) int intx2;

static __device__ __forceinline__ unsigned short f2bf(float f) {
  unsigned int u = __builtin_bit_cast(unsigned int, f);
  u += 0x7fff + ((u >> 16) & 1);          // RNE
  return (unsigned short)(u >> 16);
}
// decode 8 fp8(e4m3) packed in int2 -> accumulate into 4x floatx2 (v_pk_add_f32)
static __device__ __forceinline__ void fp8x8_acc(intx2 v, floatx2* ac) {
  ac[0] += __builtin_amdgcn_cvt_pk_f32_fp8(v[0], false);
  ac[1] += __builtin_amdgcn_cvt_pk_f32_fp8(v[0], true);
  ac[2] += __builtin_amdgcn_cvt_pk_f32_fp8(v[1], false);
  ac[3] += __builtin_amdgcn_cvt_pk_f32_fp8(v[1], true);
}

// ---------------- fused cooperative kernel: 4 phases with grid.sync ----------------
// phase 0: casts (x->bf16/fp8, W1,W2->bf16), zero sentinels + bucket_cur
// phase 1: bucket scatter (per-chunk LDS hist -> global base -> packed write)
// phase 2: per-bucket CSR (padded) + fp8 agg64 + layer-1 MFMA GEMM
// phase 3: per-bucket fp8 agg128 + layer-2 MFMA GEMM

__global__ void __launch_bounds__(512, 8) fused_gnn(
    const float* __restrict__ x,
    const float* __restrict__ Wl1, const float* __restrict__ Wr1, const float* __restrict__ b1,
    const float* __restrict__ Wl2, const float* __restrict__ Wr2, const float* __restrict__ b2,
    const int* __restrict__ src, const int* __restrict__ dst,
    unsigned short* __restrict__ xb, unsigned char* __restrict__ xq,
    unsigned short* __restrict__ W1, unsigned short* __restrict__ W2,
    int* __restrict__ bucket_cur, int* __restrict__ buf,
    int* __restrict__ row_start, int* __restrict__ row_cnt,
    unsigned short* __restrict__ h1, unsigned char* __restrict__ h1q,
    float* __restrict__ out, int E, int n) {
  cg::grid_group grid = cg::this_grid();
  __shared__ __align__(16) union {
    struct { int hist[NBUCK]; int base_s[NBUCK]; } p1;                    // 6.3 KB
    struct { int eb[BCAP]; int gsrc[BCAP];
             unsigned short aggS[64 * 72]; int cnt[64]; int tmp[64]; int cur[64]; } p2;  // 26.1 KB
    struct { int gsrcS[BCAP]; unsigned short aggS[64 * 136]; } p3;        // 25.0 KB
  } sm;
  const int t = threadIdx.x;
  const int lane = t & 63;
  const int wv = t >> 6;
  const int gid0 = blockIdx.x * 512 + t;
  const int gsz = gridDim.x * 512;

  // ================= phase 0: prep =================
  for (int i = gid0; i < n * 16; i += gsz) {       // 4 elems per iter
    float4 v = ((const float4*)x)[i];
    unsigned int lo = (unsigned int)f2bf(v.x) | ((unsigned int)f2bf(v.y) << 16);
    unsigned int hi = (unsigned int)f2bf(v.z) | ((unsigned int)f2bf(v.w) << 16);
    ((uint2*)xb)[i] = make_uint2(lo, hi);
    int q = __builtin_amdgcn_cvt_pk_fp8_f32(v.x, v.y, 0, false);
    q = __builtin_amdgcn_cvt_pk_fp8_f32(v.z, v.w, q, true);
    ((int*)xq)[i] = q;
  }
  // zero sentinel rows (index n): xq row n (64 B), h1q row n (128 B)
  if (gid0 < 16) ((int*)(xq + (size_t)n * 64))[gid0] = 0;
  if (gid0 >= 16 && gid0 < 48) ((int*)(h1q + (size_t)n * 128))[gid0 - 16] = 0;
  for (int i = gid0; i < 128 * 128; i += gsz) {
    int c = i >> 7, k = i & 127;
    W1[i] = f2bf(k < 64 ? Wl1[c * 64 + k] : Wr1[c * 64 + k - 64]);
  }
  for (int i = gid0; i < 128 * 256; i += gsz) {
    int c = i >> 8, k = i & 255;
    W2[i] = f2bf(k < 128 ? Wl2[c * 128 + k] : Wr2[c * 128 + k - 128]);
  }
  for (int i = gid0; i < NBUCK; i += gsz) bucket_cur[i] = 0;
  grid.sync();

  // ================= phase 1: bucket scatter =================
  {
    const int nchunk = (E + 4095) >> 12;           // 4096 edges per chunk
    for (int c = blockIdx.x; c < nchunk; c += gridDim.x) {
      for (int i = t; i < NBUCK; i += 512) sm.p1.hist[i] = 0;
      __syncthreads();
      const int e0 = c << 12;
#pragma unroll
      for (int p = 0; p < 8; ++p) {                // pass 1: histogram
        int e = e0 + p * 512 + t;
        if (e < E) atomicAdd(&sm.p1.hist[dst[e] >> 6], 1);
      }
      __syncthreads();
      for (int i = t; i < NBUCK; i += 512) {
        int cc = sm.p1.hist[i];
        sm.p1.base_s[i] = cc > 0 ? atomicAdd(&bucket_cur[i], cc) : 0;
      }
      __syncthreads();
      for (int i = t; i < NBUCK; i += 512) sm.p1.hist[i] = 0;   // reuse as cursor
      __syncthreads();
#pragma unroll
      for (int p = 0; p < 8; ++p) {                // pass 2: scatter (re-read edges)
        int e = e0 + p * 512 + t;
        if (e < E) {
          int s = src[e], d = dst[e];
          int bk = d >> 6;
          int sub = sm.p1.base_s[bk] + atomicAdd(&sm.p1.hist[bk], 1);
          if (sub < BCAP) buf[(bk << BSHIFT) + sub] = (s << 6) | (d & 63);
        }
      }
      __syncthreads();
    }
  }
  grid.sync();

  // ================= phase 2: CSR + agg64 + gemm1 =================
  for (int b = blockIdx.x; b < NBUCK; b += gridDim.x) {
    const int node0 = b << 6;
    const int len = min(bucket_cur[b], BCAP);
    int* reg = buf + ((size_t)b << BSHIFT);
    __syncthreads();
    if (t < 64) sm.p2.cnt[t] = 0;
    __syncthreads();
    for (int i = t; i < len; i += 512) {
      int p = reg[i];
      sm.p2.eb[i] = p;
      atomicAdd(&sm.p2.cnt[p & 63], 1);
    }
    __syncthreads();
    if (t < 64) sm.p2.tmp[t] = (sm.p2.cnt[t] + 7) & ~7;
    __syncthreads();
#pragma unroll
    for (int off = 1; off < 64; off <<= 1) {
      int u = (t >= off && t < 64) ? sm.p2.tmp[t - off] : 0;
      __syncthreads();
      if (t < 64) sm.p2.tmp[t] += u;
      __syncthreads();
    }
    if (t < 64) {
      int c8 = (sm.p2.cnt[t] + 7) & ~7;
      int ex = sm.p2.tmp[t] - c8;
      sm.p2.cur[t] = ex;
      int nd = node0 + t;
      if (nd < n) {
        row_start[nd] = (b << BSHIFT) + ex;
        row_cnt[nd] = sm.p2.cnt[t];
      }
    }
    __syncthreads();
    for (int i = t; i < len; i += 512) {
      int p = sm.p2.eb[i];
      int sub = atomicAdd(&sm.p2.cur[p & 63], 1);
      int s = p >> 6;
      if (sub < BCAP) { sm.p2.gsrc[sub] = s; reg[sub] = s; }
    }
    __syncthreads();
    if (t < 64) {                      // pad tail of each list with sentinel n
      int c8 = (sm.p2.cnt[t] + 7) & ~7;
      int e1 = sm.p2.tmp[t];
      for (int j = e1 - c8 + sm.p2.cnt[t]; j < e1; ++j)
        if (j < BCAP) { sm.p2.gsrc[j] = n; reg[j] = n; }
    }
    __syncthreads();

    // --- fp8 agg64: 8 waves, 2 nodes in flight each; branchless pipelined ---
    {
      const int eq = lane >> 3;          // edge slot 0..7
      const int cl = lane & 7;           // 8-B chunk
#pragma unroll 1
      for (int p = 0; p < 4; ++p) {
        int locA = wv + p * 16;
        int locB = locA + 8;
        int cnA = sm.p2.cnt[locA], cnB = sm.p2.cnt[locB];
        int cpA = (cnA + 7) & ~7, cpB = (cnB + 7) & ~7;
        int baseA = sm.p2.tmp[locA] - cpA;
        int baseB = sm.p2.tmp[locB] - cpB;
        floatx2 aA[4], aB[4];
#pragma unroll
        for (int j = 0; j < 4; ++j) { aA[j] = (floatx2){0.f, 0.f}; aB[j] = (floatx2){0.f, 0.f}; }
        int mx = max(cpA, cpB);
        int sA = (0 < cpA) ? sm.p2.gsrc[baseA + eq] : n;
        int sB = (0 < cpB) ? sm.p2.gsrc[baseB + eq] : n;
        intx2 vA = *(const intx2*)(xq + (size_t)sA * 64 + cl * 8);
        intx2 vB = *(const intx2*)(xq + (size_t)sB * 64 + cl * 8);
        for (int e = 8; e < mx; e += 8) {
          int sA1 = (e < cpA) ? sm.p2.gsrc[baseA + e + eq] : n;
          int sB1 = (e < cpB) ? sm.p2.gsrc[baseB + e + eq] : n;
          intx2 vA1 = *(const intx2*)(xq + (size_t)sA1 * 64 + cl * 8);
          intx2 vB1 = *(const intx2*)(xq + (size_t)sB1 * 64 + cl * 8);
          fp8x8_acc(vA, aA);
          fp8x8_acc(vB, aB);
          vA = vA1; vB = vB1;
        }
        fp8x8_acc(vA, aA);
        fp8x8_acc(vB, aB);
        float rA[8], rB[8];
#pragma unroll
        for (int j = 0; j < 4; ++j) {
          rA[2 * j] = aA[j][0]; rA[2 * j + 1] = aA[j][1];
          rB[2 * j] = aB[j][0]; rB[2 * j + 1] = aB[j][1];
        }
#pragma unroll
        for (int j = 0; j < 8; ++j) {
          rA[j] += __shfl_xor(rA[j], 8, 64);
          rA[j] += __shfl_xor(rA[j], 16, 64);
          rA[j] += __shfl_xor(rA[j], 32, 64);
          rB[j] += __shfl_xor(rB[j], 8, 64);
          rB[j] += __shfl_xor(rB[j], 16, 64);
          rB[j] += __shfl_xor(rB[j], 32, 64);
        }
        if (eq == 0) {
          float invA = 1.0f / (float)max(cnA, 1);
          float invB = 1.0f / (float)max(cnB, 1);
          short8 oA, oB;
#pragma unroll
          for (int j = 0; j < 8; ++j) { oA[j] = (short)f2bf(rA[j] * invA); oB[j] = (short)f2bf(rB[j] * invB); }
          *(short8*)(sm.p2.aggS + locA * 72 + cl * 8) = oA;
          *(short8*)(sm.p2.aggS + locB * 72 + cl * 8) = oB;
        }
      }
    }
    __syncthreads();

    // --- MFMA gemm1: 8 waves = 2 row-tiles x 4 col-tiles of 32x32; K=128 ---
    {
      const int m = lane & 15;
      const int q = lane >> 4;
      const int rw = (wv & 1) * 32;
      const int cw = (wv >> 1) * 32;
      floatx4 acc[2][2];
#pragma unroll
      for (int rt = 0; rt < 2; ++rt)
#pragma unroll
        for (int ct = 0; ct < 2; ++ct) acc[rt][ct] = (floatx4){0.f, 0.f, 0.f, 0.f};

      int ra = node0 + rw + m;      if (ra > n - 1) ra = n - 1;
      int rb = node0 + rw + 16 + m; if (rb > n - 1) rb = n - 1;
      const unsigned short* selfA0 = xb + (size_t)ra * 64 + q * 8;
      const unsigned short* selfA1 = xb + (size_t)rb * 64 + q * 8;
      const unsigned short* aggL0 = sm.p2.aggS + (rw + m) * 72 + q * 8;
      const unsigned short* aggL1 = sm.p2.aggS + (rw + 16 + m) * 72 + q * 8;
      const unsigned short* Wc0 = W1 + (size_t)(cw + m) * 128 + q * 8;
      const unsigned short* Wc1 = W1 + (size_t)(cw + 16 + m) * 128 + q * 8;

#pragma unroll
      for (int kc = 0; kc < 2; ++kc) {   // agg half: k 0..63
        short8 a0 = *(const short8*)(aggL0 + kc * 32);
        short8 a1 = *(const short8*)(aggL1 + kc * 32);
        short8 w0 = *(const short8*)(Wc0 + kc * 32);
        short8 w1 = *(const short8*)(Wc1 + kc * 32);
        acc[0][0] = __builtin_amdgcn_mfma_f32_16x16x32_bf16(a0, w0, acc[0][0], 0, 0, 0);
        acc[0][1] = __builtin_amdgcn_mfma_f32_16x16x32_bf16(a0, w1, acc[0][1], 0, 0, 0);
        acc[1][0] = __builtin_amdgcn_mfma_f32_16x16x32_bf16(a1, w0, acc[1][0], 0, 0, 0);
        acc[1][1] = __builtin_amdgcn_mfma_f32_16x16x32_bf16(a1, w1, acc[1][1], 0, 0, 0);
      }
#pragma unroll
      for (int kc = 0; kc < 2; ++kc) {   // self half: k 64..127
        short8 a0 = *(const short8*)(selfA0 + kc * 32);
        short8 a1 = *(const short8*)(selfA1 + kc * 32);
        short8 w0 = *(const short8*)(Wc0 + 64 + kc * 32);
        short8 w1 = *(const short8*)(Wc1 + 64 + kc * 32);
        acc[0][0] = __builtin_amdgcn_mfma_f32_16x16x32_bf16(a0, w0, acc[0][0], 0, 0, 0);
        acc[0][1] = __builtin_amdgcn_mfma_f32_16x16x32_bf16(a0, w1, acc[0][1], 0, 0, 0);
        acc[1][0] = __builtin_amdgcn_mfma_f32_16x16x32_bf16(a1, w0, acc[1][0], 0, 0, 0);
        acc[1][1] = __builtin_amdgcn_mfma_f32_16x16x32_bf16(a1, w1, acc[1][1], 0, 0, 0);
      }

      float bv0 = b1[cw + m], bv1 = b1[cw + 16 + m];
#pragma unroll
      for (int rt = 0; rt < 2; ++rt) {
#pragma unroll
        for (int j = 0; j < 4; ++j) {
          int row = node0 + rw + rt * 16 + q * 4 + j;
          if (row < n) {
            float v0 = acc[rt][0][j] + bv0; v0 = v0 > 0.f ? v0 : 0.f;
            float v1 = acc[rt][1][j] + bv1; v1 = v1 > 0.f ? v1 : 0.f;
            h1[(size_t)row * 128 + cw + m] = f2bf(v0);
            h1[(size_t)row * 128 + cw + 16 + m] = f2bf(v1);
            h1q[(size_t)row * 128 + cw + m] =
                (unsigned char)__builtin_amdgcn_cvt_pk_fp8_f32(v0, v0, 0, false);
            h1q[(size_t)row * 128 + cw + 16 + m] =
                (unsigned char)__builtin_amdgcn_cvt_pk_fp8_f32(v1, v1, 0, false);
          }
        }
      }
    }
    __syncthreads();
  }
  grid.sync();

  // ================= phase 3: agg128 + gemm2 =================
  for (int b = blockIdx.x; b < NBUCK; b += gridDim.x) {
    __syncthreads();                    // protect gsrcS/aggS reuse across iterations
    {
      const int4* b4 = (const int4*)(buf + ((size_t)b << BSHIFT));
      ((int4*)sm.p3.gsrcS)[t] = b4[t];  // 512 int4 = 2048 ints
    }
    __syncthreads();
    const int node0 = b << 6;

    // --- fp8 agg128: 8 waves; 2 nodes/wave in flight; branchless pipelined ---
    {
      const int eq = lane >> 4;          // edge slot 0..3
      const int cl = lane & 15;          // 8-B chunk
#pragma unroll 1
      for (int lp = 0; lp < 4; ++lp) {
        int locA = wv + lp * 16;
        int locB = locA + 8;
        int ndA = node0 + locA, ndB = node0 + locB;
        int cnA = 0, stA = 0, cnB = 0, stB = 0;
        if (ndA < n) { cnA = row_cnt[ndA]; stA = row_start[ndA] - (b << BSHIFT); }
        if (ndB < n) { cnB = row_cnt[ndB]; stB = row_start[ndB] - (b << BSHIFT); }
        int cpA = (cnA + 7) & ~7, cpB = (cnB + 7) & ~7;
        int mx = max(cpA, cpB);
        floatx2 aA[4], aB[4];
#pragma unroll
        for (int j = 0; j < 4; ++j) { aA[j] = (floatx2){0.f, 0.f}; aB[j] = (floatx2){0.f, 0.f}; }
        int sA0 = (0 < cpA) ? sm.p3.gsrcS[stA + eq] : n;
        int sA1 = (0 < cpA) ? sm.p3.gsrcS[stA + 4 + eq] : n;
        int sB0 = (0 < cpB) ? sm.p3.gsrcS[stB + eq] : n;
        int sB1 = (0 < cpB) ? sm.p3.gsrcS[stB + 4 + eq] : n;
        intx2 vA0 = *(const intx2*)(h1q + (size_t)sA0 * 128 + cl * 8);
        intx2 vA1 = *(const intx2*)(h1q + (size_t)sA1 * 128 + cl * 8);
        intx2 vB0 = *(const intx2*)(h1q + (size_t)sB0 * 128 + cl * 8);
        intx2 vB1 = *(const intx2*)(h1q + (size_t)sB1 * 128 + cl * 8);
        for (int e = 8; e < mx; e += 8) {
          int tA0 = (e < cpA) ? sm.p3.gsrcS[stA + e + eq] : n;
          int tA1 = (e < cpA) ? sm.p3.gsrcS[stA + e + 4 + eq] : n;
          int tB0 = (e < cpB) ? sm.p3.gsrcS[stB + e + eq] : n;
          int tB1 = (e < cpB) ? sm.p3.gsrcS[stB + e + 4 + eq] : n;
          intx2 wA0 = *(const intx2*)(h1q + (size_t)tA0 * 128 + cl * 8);
          intx2 wA1 = *(const intx2*)(h1q + (size_t)tA1 * 128 + cl * 8);
          intx2 wB0 = *(const intx2*)(h1q + (size_t)tB0 * 128 + cl * 8);
          intx2 wB1 = *(const intx2*)(h1q + (size_t)tB1 * 128 + cl * 8);
          fp8x8_acc(vA0, aA); fp8x8_acc(vA1, aA);
          fp8x8_acc(vB0, aB); fp8x8_acc(vB1, aB);
          vA0 = wA0; vA1 = wA1; vB0 = wB0; vB1 = wB1;
        }
        fp8x8_acc(vA0, aA); fp8x8_acc(vA1, aA);
        fp8x8_acc(vB0, aB); fp8x8_acc(vB1, aB);

        float rA[8], rB[8];
#pragma unroll
        for (int j = 0; j < 4; ++j) {
          rA[2 * j] = aA[j][0]; rA[2 * j + 1] = aA[j][1];
          rB[2 * j] = aB[j][0]; rB[2 * j + 1] = aB[j][1];
        }
#pragma unroll
        for (int j = 0; j < 8; ++j) {
          rA[j] += __shfl_xor(rA[j], 16, 64);
          rA[j] += __shfl_xor(rA[j], 32, 64);
          rB[j] += __shfl_xor(rB[j], 16, 64);
          rB[j] += __shfl_xor(rB[j], 32, 64);
        }
        if (eq == 0) {
          float invA = 1.0f / (float)max(cnA, 1);
          float invB = 1.0f / (float)max(cnB, 1);
          short8 oA, oB;
#pragma unroll
          for (int j = 0; j < 8; ++j) { oA[j] = (short)f2bf(rA[j] * invA); oB[j] = (short)f2bf(rB[j] * invB); }
          *(short8*)(sm.p3.aggS + locA * 136 + cl * 8) = oA;
          *(short8*)(sm.p3.aggS + locB * 136 + cl * 8) = oB;
        }
      }
    }
    __syncthreads();

    // --- MFMA gemm2: 8 waves = 2 row-tiles x 4 col-tiles of 32x32; K=256 ---
    {
      const int m = lane & 15;
      const int q = lane >> 4;
      const int rw = (wv & 1) * 32;
      const int cw = (wv >> 1) * 32;
      floatx4 acc[2][2];
#pragma unroll
      for (int rt = 0; rt < 2; ++rt)
#pragma unroll
        for (int ct = 0; ct < 2; ++ct) acc[rt][ct] = (floatx4){0.f, 0.f, 0.f, 0.f};

      int ra = node0 + rw + m;      if (ra > n - 1) ra = n - 1;
      int rb = node0 + rw + 16 + m; if (rb > n - 1) rb = n - 1;
      const unsigned short* selfA0 = h1 + (size_t)ra * 128 + q * 8;
      const unsigned short* selfA1 = h1 + (size_t)rb * 128 + q * 8;
      const unsigned short* aggL0 = sm.p3.aggS + (rw + m) * 136 + q * 8;
      const unsigned short* aggL1 = sm.p3.aggS + (rw + 16 + m) * 136 + q * 8;
      const unsigned short* Wc0 = W2 + (size_t)(cw + m) * 256 + q * 8;
      const unsigned short* Wc1 = W2 + (size_t)(cw + 16 + m) * 256 + q * 8;

#pragma unroll
      for (int kc = 0; kc < 4; ++kc) {   // agg half: k 0..127
        short8 a0 = *(const short8*)(aggL0 + kc * 32);
        short8 a1 = *(const short8*)(aggL1 + kc * 32);
        short8 w0 = *(const short8*)(Wc0 + kc * 32);
        short8 w1 = *(const short8*)(Wc1 + kc * 32);
        acc[0][0] = __builtin_amdgcn_mfma_f32_16x16x32_bf16(a0, w0, acc[0][0], 0, 0, 0);
        acc[0][1] = __builtin_amdgcn_mfma_f32_16x16x32_bf16(a0, w1, acc[0][1], 0, 0, 0);
        acc[1][0] = __builtin_amdgcn_mfma_f32_16x16x32_bf16(a1, w0, acc[1][0], 0, 0, 0);
        acc[1][1] = __builtin_amdgcn_mfma_f32_16x16x32_bf16(a1, w1, acc[1][1], 0, 0, 0);
      }
#pragma unroll
      for (int kc = 0; kc < 4; ++kc) {   // self half: k 128..255
        short8 a0 = *(const short8*)(selfA0 + kc * 32);
        short8 a1 = *(const short8*)(selfA1 + kc * 32);
        short8 w0 = *(const short8*)(Wc0 + 128 + kc * 32);
        short8 w1 = *(const short8*)(Wc1 + 128 + kc * 32);
        acc[0][0] = __builtin_amdgcn_mfma_f32_16x16x32_bf16(a0, w0, acc[0][0], 0, 0, 0);
        acc[0][1] = __builtin_amdgcn_mfma_f32_16x16x32_bf16(a0, w1, acc[0][1], 0, 0, 0);
        acc[1][0] = __builtin_amdgcn_mfma_f32_16x16x32_bf16(a1, w0, acc[1][0], 0, 0, 0);
        acc[1][1] = __builtin_amdgcn_mfma_f32_16x16x32_bf16(a1, w1, acc[1][1], 0, 0, 0);
      }

      float bv0 = b2[cw + m], bv1 = b2[cw + 16 + m];
#pragma unroll
      for (int rt = 0; rt < 2; ++rt) {
#pragma unroll
        for (int j = 0; j < 4; ++j) {
          int row = node0 + rw + rt * 16 + q * 4 + j;
          if (row < n) {
            float v0 = acc[rt][0][j] + bv0; v0 = v0 > 0.f ? v0 : 0.f;
            float v1 = acc[rt][1][j] + bv1; v1 = v1 > 0.f ? v1 : 0.f;
            out[(size_t)row * 128 + cw + m] = v0;
            out[(size_t)row * 128 + cw + 16 + m] = v1;
          }
        }
      }
    }
    __syncthreads();
  }
}

// ---------------- launch ----------------

extern "C" void kernel_launch(void* const* d_in, const int* in_sizes, int n_in,
                              void* d_out, int out_size, void* d_ws, size_t ws_size,
                              hipStream_t stream) {
  const int N = N_NODES;
  const int E = in_sizes[1] / 2;
  const float* x   = (const float*)d_in[0];
  const int*   src = (const int*)d_in[1];
  const int*   dst = src + E;
  const float* Wl1 = (const float*)d_in[2];
  const float* Wr1 = (const float*)d_in[3];
  const float* b1  = (const float*)d_in[4];
  const float* Wl2 = (const float*)d_in[5];
  const float* Wr2 = (const float*)d_in[6];
  const float* b2  = (const float*)d_in[7];
  float* out = (float*)d_out;

  // workspace (~36 MB)
  unsigned short* xb = (unsigned short*)d_ws;         // N*64 bf16 (x cast)
  unsigned short* h1 = xb + (size_t)N * 64;           // N*128 bf16 (layer-1 out)
  unsigned short* W1 = h1 + (size_t)N * 128;          // 128*128
  unsigned short* W2 = W1 + 128 * 128;                // 128*256
  int* row_start  = (int*)(W2 + 128 * 256);           // N
  int* row_cnt    = row_start + N;                    // N
  int* bucket_cur = row_cnt + N;                      // NBUCK (padded to 784)
  int* buf        = bucket_cur + 784;                 // NBUCK*BCAP ints (6.4 MB)
  unsigned char* xq  = (unsigned char*)(buf + (size_t)NBUCK * BCAP);  // (N+1)*64 fp8
  unsigned char* h1q = xq + ((size_t)N + 1) * 64;                     // (N+1)*128 fp8

  static int grid_blocks = 0;
  if (grid_blocks == 0) {
    int nb = 0;
    (void)hipOccupancyMaxActiveBlocksPerMultiprocessor(&nb, fused_gnn, 512, 0);
    if (nb < 1) nb = 1;
    if (nb > 4) nb = 4;
    grid_blocks = nb * 256;
  }

  int Ee = E, Nn = N;
  void* args[] = { (void*)&x, (void*)&Wl1, (void*)&Wr1, (void*)&b1,
                   (void*)&Wl2, (void*)&Wr2, (void*)&b2,
                   (void*)&src, (void*)&dst,
                   (void*)&xb, (void*)&xq, (void*)&W1, (void*)&W2,
                   (void*)&bucket_cur, (void*)&buf,
                   (void*)&row_start, (void*)&row_cnt,
                   (void*)&h1, (void*)&h1q, (void*)&out,
                   (void*)&Ee, (void*)&Nn };
  (void)hipLaunchCooperativeKernel(fused_gnn, dim3(grid_blocks), dim3(512),
                                   args, 0, stream);
}

// Round 6
// 193.357 us; speedup vs baseline: 2.0765x; 2.0765x over previous
//
#include <hip/hip_runtime.h>

#define N_NODES 50000
#define NBUCK 782        // ceil(N_NODES / 64) -- 64 dst-nodes per bucket
#define BCAP 2048        // slots per bucket (mean fill 1024 + pad <=448)
#define BSHIFT 11

typedef __attribute__((ext_vector_type(8))) short short8;
typedef __attribute__((ext_vector_type(4))) float floatx4;
typedef __attribute__((ext_vector_type(2))) float floatx2;
typedef __attribute__((ext_vector_type(2))) int intx2;

static __device__ __forceinline__ unsigned short f2bf(float f) {
  unsigned int u = __builtin_bit_cast(unsigned int, f);
  u += 0x7fff + ((u >> 16) & 1);          // RNE
  return (unsigned short)(u >> 16);
}
// decode 8 fp8(e4m3) packed in int2 -> accumulate into 4x floatx2 (v_pk_add_f32)
static __device__ __forceinline__ void fp8x8_acc(intx2 v, floatx2* ac) {
  ac[0] += __builtin_amdgcn_cvt_pk_f32_fp8(v[0], false);
  ac[1] += __builtin_amdgcn_cvt_pk_f32_fp8(v[0], true);
  ac[2] += __builtin_amdgcn_cvt_pk_f32_fp8(v[1], false);
  ac[3] += __builtin_amdgcn_cvt_pk_f32_fp8(v[1], true);
}

// ---------------- K1: casts (x -> bf16 + fp8; W1,W2 -> bf16) + sentinel zero ----------------

__global__ void __launch_bounds__(512) prep_cast(
    const float* __restrict__ x,
    const float* __restrict__ Wl1, const float* __restrict__ Wr1,
    const float* __restrict__ Wl2, const float* __restrict__ Wr2,
    unsigned short* __restrict__ xb, unsigned char* __restrict__ xq,
    unsigned short* __restrict__ W1, unsigned short* __restrict__ W2,
    unsigned char* __restrict__ h1q, int n) {
  const int gid = blockIdx.x * 512 + threadIdx.x;
  const int gsz = gridDim.x * 512;
  for (int i = gid; i < n * 16; i += gsz) {       // 4 elems per iter
    float4 v = ((const float4*)x)[i];
    unsigned int lo = (unsigned int)f2bf(v.x) | ((unsigned int)f2bf(v.y) << 16);
    unsigned int hi = (unsigned int)f2bf(v.z) | ((unsigned int)f2bf(v.w) << 16);
    ((uint2*)xb)[i] = make_uint2(lo, hi);
    int q = __builtin_amdgcn_cvt_pk_fp8_f32(v.x, v.y, 0, false);
    q = __builtin_amdgcn_cvt_pk_fp8_f32(v.z, v.w, q, true);
    ((int*)xq)[i] = q;
  }
  // zero sentinel rows (index n): xq row n (64 B), h1q row n (128 B)
  if (gid < 16) ((int*)(xq + (size_t)n * 64))[gid] = 0;
  if (gid >= 16 && gid < 48) ((int*)(h1q + (size_t)n * 128))[gid - 16] = 0;
  for (int i = gid; i < 128 * 128; i += gsz) {
    int c = i >> 7, k = i & 127;
    W1[i] = f2bf(k < 64 ? Wl1[c * 64 + k] : Wr1[c * 64 + k - 64]);
  }
  for (int i = gid; i < 128 * 256; i += gsz) {
    int c = i >> 8, k = i & 255;
    W2[i] = f2bf(k < 128 ? Wl2[c * 128 + k] : Wr2[c * 128 + k - 128]);
  }
}

// ---------------- K2: bucket scatter ----------------

__global__ void __launch_bounds__(512) scatter(
    const int* __restrict__ src, const int* __restrict__ dst,
    int* __restrict__ bucket_cur, int* __restrict__ buf, int E) {
  __shared__ int hist[NBUCK];
  __shared__ int base_s[NBUCK];
  const int t = threadIdx.x;
  for (int i = t; i < NBUCK; i += 512) hist[i] = 0;
  __syncthreads();
  int e0 = blockIdx.x * 4096;
  int sv[8], dv[8], bv[8];
#pragma unroll
  for (int p = 0; p < 8; ++p) {
    int e = e0 + p * 512 + t;
    if (e < E) {
      sv[p] = src[e];
      dv[p] = dst[e];
      bv[p] = dv[p] >> 6;
      atomicAdd(&hist[bv[p]], 1);
    } else bv[p] = -1;
  }
  __syncthreads();
  for (int i = t; i < NBUCK; i += 512) {
    int c = hist[i];
    base_s[i] = c > 0 ? atomicAdd(&bucket_cur[i], c) : 0;
  }
  __syncthreads();
  for (int i = t; i < NBUCK; i += 512) hist[i] = 0;   // reuse as sub-cursor
  __syncthreads();
#pragma unroll
  for (int p = 0; p < 8; ++p) {
    if (bv[p] >= 0) {
      int sub = base_s[bv[p]] + atomicAdd(&hist[bv[p]], 1);
      if (sub < BCAP) buf[(bv[p] << BSHIFT) + sub] = (sv[p] << 6) | (dv[p] & 63);
    }
  }
}

// ---------------- K3: per-bucket CSR build (grouped src lists, sentinel-padded) ----------------

__global__ void __launch_bounds__(512) csr_build(
    int* __restrict__ buf, const int* __restrict__ bucket_cur,
    int* __restrict__ row_start, int* __restrict__ row_cnt, int n) {
  __shared__ int eb[BCAP];
  __shared__ int cnt[64];
  __shared__ int tmp[64];
  __shared__ int cur[64];
  const int t = threadIdx.x;
  const int b = blockIdx.x;
  const int node0 = b << 6;
  const int len = min(bucket_cur[b], BCAP);
  int* reg = buf + ((size_t)b << BSHIFT);

  if (t < 64) cnt[t] = 0;
  __syncthreads();
  for (int i = t; i < len; i += 512) {
    int p = reg[i];
    eb[i] = p;
    atomicAdd(&cnt[p & 63], 1);
  }
  __syncthreads();
  if (t < 64) tmp[t] = (cnt[t] + 7) & ~7;
  __syncthreads();
#pragma unroll
  for (int off = 1; off < 64; off <<= 1) {
    int u = (t >= off && t < 64) ? tmp[t - off] : 0;
    __syncthreads();
    if (t < 64) tmp[t] += u;
    __syncthreads();
  }
  if (t < 64) {
    int c8 = (cnt[t] + 7) & ~7;
    int ex = tmp[t] - c8;
    cur[t] = ex;
    int nd = node0 + t;
    if (nd < n) {
      row_start[nd] = (b << BSHIFT) + ex;
      row_cnt[nd] = cnt[t];
    }
  }
  __syncthreads();
  for (int i = t; i < len; i += 512) {
    int p = eb[i];
    int sub = atomicAdd(&cur[p & 63], 1);
    if (sub < BCAP) reg[sub] = p >> 6;               // grouped src list
  }
  __syncthreads();
  if (t < 64) {                       // pad tail of each list with sentinel n
    int c8 = (cnt[t] + 7) & ~7;
    int e1 = tmp[t];
    for (int j = e1 - c8 + cnt[t]; j < e1; ++j)
      if (j < BCAP) reg[j] = n;
  }
}

// ---------------- K4: fp8 agg64 (branchless, pipelined) + layer-1 MFMA GEMM ----------------

__global__ void __launch_bounds__(512, 6) agg_gemm1(
    const unsigned short* __restrict__ xb, const unsigned char* __restrict__ xq,
    const int* __restrict__ row_start, const int* __restrict__ row_cnt,
    const int* __restrict__ buf, const unsigned short* __restrict__ W1,
    const float* __restrict__ b1,
    unsigned short* __restrict__ h1, unsigned char* __restrict__ h1q, int n) {
  __shared__ int gsrcS[BCAP];                            // 8 KB staged indices
  __shared__ __align__(16) unsigned short aggS[64 * 72]; // 9 KB agg tile
  const int t = threadIdx.x;
  const int lane = t & 63;
  const int wv = t >> 6;
  const int node0 = blockIdx.x << 6;
  const int boff = blockIdx.x << BSHIFT;

  {
    const int4* b4 = (const int4*)(buf + ((size_t)blockIdx.x << BSHIFT));
    ((int4*)gsrcS)[t] = b4[t];
  }
  __syncthreads();

  // --- fp8 agg64: 8 waves, 2 nodes in flight each; 8 edge-slots x 8-B chunks ---
  const int eq = lane >> 3;            // edge slot 0..7
  const int cl = lane & 7;             // 8-B chunk: cols cl*8..cl*8+7
#pragma unroll 1
  for (int p = 0; p < 4; ++p) {
    int locA = wv + p * 16;
    int locB = locA + 8;
    int ndA = node0 + locA, ndB = node0 + locB;
    int cnA = 0, stA = 0, cnB = 0, stB = 0;
    if (ndA < n) { cnA = row_cnt[ndA]; stA = row_start[ndA] - boff; }
    if (ndB < n) { cnB = row_cnt[ndB]; stB = row_start[ndB] - boff; }
    int cpA = (cnA + 7) & ~7, cpB = (cnB + 7) & ~7;
    floatx2 aA[4], aB[4];
#pragma unroll
    for (int j = 0; j < 4; ++j) { aA[j] = (floatx2){0.f, 0.f}; aB[j] = (floatx2){0.f, 0.f}; }
    int mx = max(cpA, cpB);
    int sA = (0 < cpA) ? gsrcS[stA + eq] : n;
    int sB = (0 < cpB) ? gsrcS[stB + eq] : n;
    intx2 vA = *(const intx2*)(xq + (size_t)sA * 64 + cl * 8);
    intx2 vB = *(const intx2*)(xq + (size_t)sB * 64 + cl * 8);
    for (int e = 8; e < mx; e += 8) {
      int sA1 = (e < cpA) ? gsrcS[stA + e + eq] : n;
      int sB1 = (e < cpB) ? gsrcS[stB + e + eq] : n;
      intx2 vA1 = *(const intx2*)(xq + (size_t)sA1 * 64 + cl * 8);
      intx2 vB1 = *(const intx2*)(xq + (size_t)sB1 * 64 + cl * 8);
      fp8x8_acc(vA, aA);
      fp8x8_acc(vB, aB);
      vA = vA1; vB = vB1;
    }
    fp8x8_acc(vA, aA);
    fp8x8_acc(vB, aB);
    float rA[8], rB[8];
#pragma unroll
    for (int j = 0; j < 4; ++j) {
      rA[2 * j] = aA[j][0]; rA[2 * j + 1] = aA[j][1];
      rB[2 * j] = aB[j][0]; rB[2 * j + 1] = aB[j][1];
    }
#pragma unroll
    for (int j = 0; j < 8; ++j) {
      rA[j] += __shfl_xor(rA[j], 8, 64);
      rA[j] += __shfl_xor(rA[j], 16, 64);
      rA[j] += __shfl_xor(rA[j], 32, 64);
      rB[j] += __shfl_xor(rB[j], 8, 64);
      rB[j] += __shfl_xor(rB[j], 16, 64);
      rB[j] += __shfl_xor(rB[j], 32, 64);
    }
    if (eq == 0) {
      float invA = 1.0f / (float)max(cnA, 1);
      float invB = 1.0f / (float)max(cnB, 1);
      short8 oA, oB;
#pragma unroll
      for (int j = 0; j < 8; ++j) { oA[j] = (short)f2bf(rA[j] * invA); oB[j] = (short)f2bf(rB[j] * invB); }
      *(short8*)(aggS + locA * 72 + cl * 8) = oA;
      *(short8*)(aggS + locB * 72 + cl * 8) = oB;
    }
  }
  __syncthreads();

  // --- MFMA gemm1: 8 waves = 2 row-tiles x 4 col-tiles of 32x32; K=128 ---
  const int m = lane & 15;
  const int q = lane >> 4;
  const int rw = (wv & 1) * 32;
  const int cw = (wv >> 1) * 32;
  floatx4 acc[2][2];
#pragma unroll
  for (int rt = 0; rt < 2; ++rt)
#pragma unroll
    for (int ct = 0; ct < 2; ++ct) acc[rt][ct] = (floatx4){0.f, 0.f, 0.f, 0.f};

  int ra = node0 + rw + m;      if (ra > n - 1) ra = n - 1;
  int rb = node0 + rw + 16 + m; if (rb > n - 1) rb = n - 1;
  const unsigned short* selfA0 = xb + (size_t)ra * 64 + q * 8;
  const unsigned short* selfA1 = xb + (size_t)rb * 64 + q * 8;
  const unsigned short* aggL0 = aggS + (rw + m) * 72 + q * 8;
  const unsigned short* aggL1 = aggS + (rw + 16 + m) * 72 + q * 8;
  const unsigned short* Wc0 = W1 + (size_t)(cw + m) * 128 + q * 8;
  const unsigned short* Wc1 = W1 + (size_t)(cw + 16 + m) * 128 + q * 8;

#pragma unroll
  for (int kc = 0; kc < 2; ++kc) {     // agg half: k 0..63
    short8 a0 = *(const short8*)(aggL0 + kc * 32);
    short8 a1 = *(const short8*)(aggL1 + kc * 32);
    short8 w0 = *(const short8*)(Wc0 + kc * 32);
    short8 w1 = *(const short8*)(Wc1 + kc * 32);
    acc[0][0] = __builtin_amdgcn_mfma_f32_16x16x32_bf16(a0, w0, acc[0][0], 0, 0, 0);
    acc[0][1] = __builtin_amdgcn_mfma_f32_16x16x32_bf16(a0, w1, acc[0][1], 0, 0, 0);
    acc[1][0] = __builtin_amdgcn_mfma_f32_16x16x32_bf16(a1, w0, acc[1][0], 0, 0, 0);
    acc[1][1] = __builtin_amdgcn_mfma_f32_16x16x32_bf16(a1, w1, acc[1][1], 0, 0, 0);
  }
#pragma unroll
  for (int kc = 0; kc < 2; ++kc) {     // self half: k 64..127
    short8 a0 = *(const short8*)(selfA0 + kc * 32);
    short8 a1 = *(const short8*)(selfA1 + kc * 32);
    short8 w0 = *(const short8*)(Wc0 + 64 + kc * 32);
    short8 w1 = *(const short8*)(Wc1 + 64 + kc * 32);
    acc[0][0] = __builtin_amdgcn_mfma_f32_16x16x32_bf16(a0, w0, acc[0][0], 0, 0, 0);
    acc[0][1] = __builtin_amdgcn_mfma_f32_16x16x32_bf16(a0, w1, acc[0][1], 0, 0, 0);
    acc[1][0] = __builtin_amdgcn_mfma_f32_16x16x32_bf16(a1, w0, acc[1][0], 0, 0, 0);
    acc[1][1] = __builtin_amdgcn_mfma_f32_16x16x32_bf16(a1, w1, acc[1][1], 0, 0, 0);
  }

  float bv0 = b1[cw + m], bv1 = b1[cw + 16 + m];
#pragma unroll
  for (int rt = 0; rt < 2; ++rt) {
#pragma unroll
    for (int j = 0; j < 4; ++j) {
      int row = node0 + rw + rt * 16 + q * 4 + j;
      if (row < n) {
        float v0 = acc[rt][0][j] + bv0; v0 = v0 > 0.f ? v0 : 0.f;
        float v1 = acc[rt][1][j] + bv1; v1 = v1 > 0.f ? v1 : 0.f;
        h1[(size_t)row * 128 + cw + m] = f2bf(v0);
        h1[(size_t)row * 128 + cw + 16 + m] = f2bf(v1);
        h1q[(size_t)row * 128 + cw + m] =
            (unsigned char)__builtin_amdgcn_cvt_pk_fp8_f32(v0, v0, 0, false);
        h1q[(size_t)row * 128 + cw + 16 + m] =
            (unsigned char)__builtin_amdgcn_cvt_pk_fp8_f32(v1, v1, 0, false);
      }
    }
  }
}

// ---------------- K5: fp8 agg128 (branchless, pipelined) + layer-2 MFMA GEMM ----------------

__global__ void __launch_bounds__(512, 6) agg_gemm2(
    const unsigned short* __restrict__ h1, const unsigned char* __restrict__ h1q,
    const int* __restrict__ row_start, const int* __restrict__ row_cnt,
    const int* __restrict__ buf, const unsigned short* __restrict__ W2,
    const float* __restrict__ b2, float* __restrict__ out, int n) {
  __shared__ int gsrcS[BCAP];                             // 8 KB staged indices
  __shared__ __align__(16) unsigned short aggS[64 * 136]; // 17 KB (pad 128->136)
  const int t = threadIdx.x;
  const int lane = t & 63;
  const int wv = t >> 6;
  const int node0 = blockIdx.x << 6;

  {
    const int4* b4 = (const int4*)(buf + ((size_t)blockIdx.x << BSHIFT));
    ((int4*)gsrcS)[t] = b4[t];
  }
  __syncthreads();

  // --- fp8 agg128: 8 waves; 2 nodes/wave in flight; 4 edge-slots x 2 chains x 8-B chunks ---
  const int eq = lane >> 4;            // edge slot 0..3
  const int cl = lane & 15;            // 8-B chunk: cols cl*8..cl*8+7
#pragma unroll 1
  for (int lp = 0; lp < 4; ++lp) {
    int locA = wv + lp * 16;
    int locB = locA + 8;
    int ndA = node0 + locA, ndB = node0 + locB;
    int cnA = 0, stA = 0, cnB = 0, stB = 0;
    if (ndA < n) { cnA = row_cnt[ndA]; stA = row_start[ndA] - (blockIdx.x << BSHIFT); }
    if (ndB < n) { cnB = row_cnt[ndB]; stB = row_start[ndB] - (blockIdx.x << BSHIFT); }
    int cpA = (cnA + 7) & ~7, cpB = (cnB + 7) & ~7;
    int mx = max(cpA, cpB);
    floatx2 aA[4], aB[4];
#pragma unroll
    for (int j = 0; j < 4; ++j) { aA[j] = (floatx2){0.f, 0.f}; aB[j] = (floatx2){0.f, 0.f}; }
    int sA0 = (0 < cpA) ? gsrcS[stA + eq] : n;
    int sA1 = (0 < cpA) ? gsrcS[stA + 4 + eq] : n;
    int sB0 = (0 < cpB) ? gsrcS[stB + eq] : n;
    int sB1 = (0 < cpB) ? gsrcS[stB + 4 + eq] : n;
    intx2 vA0 = *(const intx2*)(h1q + (size_t)sA0 * 128 + cl * 8);
    intx2 vA1 = *(const intx2*)(h1q + (size_t)sA1 * 128 + cl * 8);
    intx2 vB0 = *(const intx2*)(h1q + (size_t)sB0 * 128 + cl * 8);
    intx2 vB1 = *(const intx2*)(h1q + (size_t)sB1 * 128 + cl * 8);
    for (int e = 8; e < mx; e += 8) {  // prefetch next 4 before decoding current 4
      int tA0 = (e < cpA) ? gsrcS[stA + e + eq] : n;
      int tA1 = (e < cpA) ? gsrcS[stA + e + 4 + eq] : n;
      int tB0 = (e < cpB) ? gsrcS[stB + e + eq] : n;
      int tB1 = (e < cpB) ? gsrcS[stB + e + 4 + eq] : n;
      intx2 wA0 = *(const intx2*)(h1q + (size_t)tA0 * 128 + cl * 8);
      intx2 wA1 = *(const intx2*)(h1q + (size_t)tA1 * 128 + cl * 8);
      intx2 wB0 = *(const intx2*)(h1q + (size_t)tB0 * 128 + cl * 8);
      intx2 wB1 = *(const intx2*)(h1q + (size_t)tB1 * 128 + cl * 8);
      fp8x8_acc(vA0, aA); fp8x8_acc(vA1, aA);
      fp8x8_acc(vB0, aB); fp8x8_acc(vB1, aB);
      vA0 = wA0; vA1 = wA1; vB0 = wB0; vB1 = wB1;
    }
    fp8x8_acc(vA0, aA); fp8x8_acc(vA1, aA);
    fp8x8_acc(vB0, aB); fp8x8_acc(vB1, aB);

    float rA[8], rB[8];
#pragma unroll
    for (int j = 0; j < 4; ++j) {
      rA[2 * j] = aA[j][0]; rA[2 * j + 1] = aA[j][1];
      rB[2 * j] = aB[j][0]; rB[2 * j + 1] = aB[j][1];
    }
#pragma unroll
    for (int j = 0; j < 8; ++j) {
      rA[j] += __shfl_xor(rA[j], 16, 64);
      rA[j] += __shfl_xor(rA[j], 32, 64);
      rB[j] += __shfl_xor(rB[j], 16, 64);
      rB[j] += __shfl_xor(rB[j], 32, 64);
    }
    if (eq == 0) {
      float invA = 1.0f / (float)max(cnA, 1);
      float invB = 1.0f / (float)max(cnB, 1);
      short8 oA, oB;
#pragma unroll
      for (int j = 0; j < 8; ++j) { oA[j] = (short)f2bf(rA[j] * invA); oB[j] = (short)f2bf(rB[j] * invB); }
      *(short8*)(aggS + locA * 136 + cl * 8) = oA;
      *(short8*)(aggS + locB * 136 + cl * 8) = oB;
    }
  }
  __syncthreads();

  // --- MFMA gemm2: 8 waves = 2 row-tiles x 4 col-tiles of 32x32; K=256 ---
  const int m = lane & 15;
  const int q = lane >> 4;
  const int rw = (wv & 1) * 32;
  const int cw = (wv >> 1) * 32;
  floatx4 acc[2][2];
#pragma unroll
  for (int rt = 0; rt < 2; ++rt)
#pragma unroll
    for (int ct = 0; ct < 2; ++ct) acc[rt][ct] = (floatx4){0.f, 0.f, 0.f, 0.f};

  int ra = node0 + rw + m;      if (ra > n - 1) ra = n - 1;
  int rb = node0 + rw + 16 + m; if (rb > n - 1) rb = n - 1;
  const unsigned short* selfA0 = h1 + (size_t)ra * 128 + q * 8;
  const unsigned short* selfA1 = h1 + (size_t)rb * 128 + q * 8;
  const unsigned short* aggL0 = aggS + (rw + m) * 136 + q * 8;
  const unsigned short* aggL1 = aggS + (rw + 16 + m) * 136 + q * 8;
  const unsigned short* Wc0 = W2 + (size_t)(cw + m) * 256 + q * 8;
  const unsigned short* Wc1 = W2 + (size_t)(cw + 16 + m) * 256 + q * 8;

#pragma unroll
  for (int kc = 0; kc < 4; ++kc) {     // agg half: k 0..127
    short8 a0 = *(const short8*)(aggL0 + kc * 32);
    short8 a1 = *(const short8*)(aggL1 + kc * 32);
    short8 w0 = *(const short8*)(Wc0 + kc * 32);
    short8 w1 = *(const short8*)(Wc1 + kc * 32);
    acc[0][0] = __builtin_amdgcn_mfma_f32_16x16x32_bf16(a0, w0, acc[0][0], 0, 0, 0);
    acc[0][1] = __builtin_amdgcn_mfma_f32_16x16x32_bf16(a0, w1, acc[0][1], 0, 0, 0);
    acc[1][0] = __builtin_amdgcn_mfma_f32_16x16x32_bf16(a1, w0, acc[1][0], 0, 0, 0);
    acc[1][1] = __builtin_amdgcn_mfma_f32_16x16x32_bf16(a1, w1, acc[1][1], 0, 0, 0);
  }
#pragma unroll
  for (int kc = 0; kc < 4; ++kc) {     // self half: k 128..255
    short8 a0 = *(const short8*)(selfA0 + kc * 32);
    short8 a1 = *(const short8*)(selfA1 + kc * 32);
    short8 w0 = *(const short8*)(Wc0 + 128 + kc * 32);
    short8 w1 = *(const short8*)(Wc1 + 128 + kc * 32);
    acc[0][0] = __builtin_amdgcn_mfma_f32_16x16x32_bf16(a0, w0, acc[0][0], 0, 0, 0);
    acc[0][1] = __builtin_amdgcn_mfma_f32_16x16x32_bf16(a0, w1, acc[0][1], 0, 0, 0);
    acc[1][0] = __builtin_amdgcn_mfma_f32_16x16x32_bf16(a1, w0, acc[1][0], 0, 0, 0);
    acc[1][1] = __builtin_amdgcn_mfma_f32_16x16x32_bf16(a1, w1, acc[1][1], 0, 0, 0);
  }

  float bv0 = b2[cw + m], bv1 = b2[cw + 16 + m];
#pragma unroll
  for (int rt = 0; rt < 2; ++rt) {
#pragma unroll
    for (int j = 0; j < 4; ++j) {
      int row = node0 + rw + rt * 16 + q * 4 + j;
      if (row < n) {
        float v0 = acc[rt][0][j] + bv0; v0 = v0 > 0.f ? v0 : 0.f;
        float v1 = acc[rt][1][j] + bv1; v1 = v1 > 0.f ? v1 : 0.f;
        out[(size_t)row * 128 + cw + m] = v0;
        out[(size_t)row * 128 + cw + 16 + m] = v1;
      }
    }
  }
}

// ---------------- launch ----------------

extern "C" void kernel_launch(void* const* d_in, const int* in_sizes, int n_in,
                              void* d_out, int out_size, void* d_ws, size_t ws_size,
                              hipStream_t stream) {
  const int N = N_NODES;
  const int E = in_sizes[1] / 2;
  const float* x   = (const float*)d_in[0];
  const int*   src = (const int*)d_in[1];
  const int*   dst = src + E;
  const float* Wl1 = (const float*)d_in[2];
  const float* Wr1 = (const float*)d_in[3];
  const float* b1  = (const float*)d_in[4];
  const float* Wl2 = (const float*)d_in[5];
  const float* Wr2 = (const float*)d_in[6];
  const float* b2  = (const float*)d_in[7];
  float* out = (float*)d_out;

  // workspace (~36 MB)
  unsigned short* xb = (unsigned short*)d_ws;         // N*64 bf16 (x cast)
  unsigned short* h1 = xb + (size_t)N * 64;           // N*128 bf16 (layer-1 out)
  unsigned short* W1 = h1 + (size_t)N * 128;          // 128*128
  unsigned short* W2 = W1 + 128 * 128;                // 128*256
  int* row_start  = (int*)(W2 + 128 * 256);           // N
  int* row_cnt    = row_start + N;                    // N
  int* bucket_cur = row_cnt + N;                      // NBUCK (padded to 784)
  int* buf        = bucket_cur + 784;                 // NBUCK*BCAP ints (6.4 MB)
  unsigned char* xq  = (unsigned char*)(buf + (size_t)NBUCK * BCAP);  // (N+1)*64 fp8
  unsigned char* h1q = xq + ((size_t)N + 1) * 64;                     // (N+1)*128 fp8

  (void)hipMemsetAsync(bucket_cur, 0, NBUCK * sizeof(int), stream);
  prep_cast<<<391, 512, 0, stream>>>(x, Wl1, Wr1, Wl2, Wr2, xb, xq, W1, W2, h1q, N);
  int sb = (E + 4095) / 4096;                         // 196 blocks
  scatter<<<sb, 512, 0, stream>>>(src, dst, bucket_cur, buf, E);
  csr_build<<<NBUCK, 512, 0, stream>>>(buf, bucket_cur, row_start, row_cnt, N);
  agg_gemm1<<<NBUCK, 512, 0, stream>>>(xb, xq, row_start, row_cnt, buf, W1, b1,
                                       h1, h1q, N);
  agg_gemm2<<<NBUCK, 512, 0, stream>>>(h1, h1q, row_start, row_cnt, buf, W2, b2, out, N);
}

// Round 7
// 181.449 us; speedup vs baseline: 2.2128x; 1.0656x over previous
//
#include <hip/hip_runtime.h>

#define N_NODES 50000
#define NBUCK 782        // ceil(N_NODES / 64) -- 64 dst-nodes per bucket
#define BCAP 2048        // slots per bucket (mean fill 1024 + pad <=448)
#define BSHIFT 11

typedef __attribute__((ext_vector_type(8))) short short8;
typedef __attribute__((ext_vector_type(4))) float floatx4;
typedef __attribute__((ext_vector_type(2))) float floatx2;
typedef __attribute__((ext_vector_type(2))) int intx2;

static __device__ __forceinline__ unsigned short f2bf(float f) {
  unsigned int u = __builtin_bit_cast(unsigned int, f);
  u += 0x7fff + ((u >> 16) & 1);          // RNE
  return (unsigned short)(u >> 16);
}
// decode 8 fp8(e4m3) packed in int2 -> accumulate into 4x floatx2 (v_pk_add_f32)
static __device__ __forceinline__ void fp8x8_acc(intx2 v, floatx2* ac) {
  ac[0] += __builtin_amdgcn_cvt_pk_f32_fp8(v[0], false);
  ac[1] += __builtin_amdgcn_cvt_pk_f32_fp8(v[0], true);
  ac[2] += __builtin_amdgcn_cvt_pk_f32_fp8(v[1], false);
  ac[3] += __builtin_amdgcn_cvt_pk_f32_fp8(v[1], true);
}

// ---------------- K1: prep (casts incl. fp8 copy + zero sentinel rows) + bucket scatter ----------------

__global__ void __launch_bounds__(512) prep_scatter(
    const float* __restrict__ x,
    const float* __restrict__ Wl1, const float* __restrict__ Wr1,
    const float* __restrict__ Wl2, const float* __restrict__ Wr2,
    unsigned short* __restrict__ xb, unsigned char* __restrict__ xq,
    unsigned short* __restrict__ W1, unsigned short* __restrict__ W2,
    const int* __restrict__ src, const int* __restrict__ dst,
    int* __restrict__ bucket_cur, int* __restrict__ buf, int E, int n) {
  const int t = threadIdx.x;
  const int gid = blockIdx.x * 512 + t;
  const int gsz = gridDim.x * 512;
  for (int i = gid; i < n * 16; i += gsz) {       // 4 elems per iter
    float4 v = ((const float4*)x)[i];
    unsigned int lo = (unsigned int)f2bf(v.x) | ((unsigned int)f2bf(v.y) << 16);
    unsigned int hi = (unsigned int)f2bf(v.z) | ((unsigned int)f2bf(v.w) << 16);
    ((uint2*)xb)[i] = make_uint2(lo, hi);
    int q = __builtin_amdgcn_cvt_pk_fp8_f32(v.x, v.y, 0, false);
    q = __builtin_amdgcn_cvt_pk_fp8_f32(v.z, v.w, q, true);
    ((int*)xq)[i] = q;
  }
  // zero sentinel rows (index n): xq row n (64 B), h1q row n (128 B)
  {
    unsigned char* h1q = xq + ((size_t)n + 1) * 64;
    if (gid < 16) ((int*)(xq + (size_t)n * 64))[gid] = 0;
    if (gid >= 16 && gid < 48) ((int*)(h1q + (size_t)n * 128))[gid - 16] = 0;
  }
  for (int i = gid; i < 128 * 128; i += gsz) {
    int c = i >> 7, k = i & 127;
    W1[i] = f2bf(k < 64 ? Wl1[c * 64 + k] : Wr1[c * 64 + k - 64]);
  }
  for (int i = gid; i < 128 * 256; i += gsz) {
    int c = i >> 8, k = i & 255;
    W2[i] = f2bf(k < 128 ? Wl2[c * 128 + k] : Wr2[c * 128 + k - 128]);
  }

  // scatter: block handles chunk of 4096 edges; packed = (src<<6)|(dst&63)
  __shared__ int hist[NBUCK];
  __shared__ int base_s[NBUCK];
  for (int i = t; i < NBUCK; i += 512) hist[i] = 0;
  __syncthreads();
  int e0 = blockIdx.x * 4096;
  int sv[8], dv[8], bv[8];
#pragma unroll
  for (int p = 0; p < 8; ++p) {
    int e = e0 + p * 512 + t;
    if (e < E) {
      sv[p] = src[e];
      dv[p] = dst[e];
      bv[p] = dv[p] >> 6;
      atomicAdd(&hist[bv[p]], 1);
    } else bv[p] = -1;
  }
  __syncthreads();
  for (int i = t; i < NBUCK; i += 512) {
    int c = hist[i];
    base_s[i] = c > 0 ? atomicAdd(&bucket_cur[i], c) : 0;
  }
  __syncthreads();
  for (int i = t; i < NBUCK; i += 512) hist[i] = 0;   // reuse as sub-cursor
  __syncthreads();
#pragma unroll
  for (int p = 0; p < 8; ++p) {
    if (bv[p] >= 0) {
      int sub = base_s[bv[p]] + atomicAdd(&hist[bv[p]], 1);
      if (sub < BCAP) buf[(bv[p] << BSHIFT) + sub] = (sv[p] << 6) | (dv[p] & 63);
    }
  }
}

// ---------------- K2: bucket CSR (padded) + fp8 agg64 (2-deep prefetch) + layer-1 MFMA GEMM ----------------

__global__ void __launch_bounds__(512, 6) csr_agg_gemm1(
    int* __restrict__ buf, const int* __restrict__ bucket_cur,
    int* __restrict__ row_start, int* __restrict__ row_cnt,
    const unsigned short* __restrict__ xb, const unsigned char* __restrict__ xq,
    const unsigned short* __restrict__ W1, const float* __restrict__ b1,
    unsigned short* __restrict__ h1, unsigned char* __restrict__ h1q, int n) {
  __shared__ int eb[BCAP];                            // 8 KB staged packed edges
  __shared__ int gsrc[BCAP];                          // 8 KB grouped src lists
  __shared__ __align__(16) unsigned short aggS[64 * 72];  // 9 KB agg tile
  __shared__ int cnt[64];
  __shared__ int tmp[64];
  __shared__ int cur[64];
  const int t = threadIdx.x;
  const int b = blockIdx.x;
  const int node0 = b << 6;
  const int len = min(bucket_cur[b], BCAP);
  int* reg = buf + (b << BSHIFT);

  // --- CSR build (prefix over counts padded to multiple of 8) ---
  if (t < 64) cnt[t] = 0;
  __syncthreads();
  for (int i = t; i < len; i += 512) {
    int p = reg[i];
    eb[i] = p;
    atomicAdd(&cnt[p & 63], 1);
  }
  __syncthreads();
  if (t < 64) tmp[t] = (cnt[t] + 7) & ~7;
  __syncthreads();
#pragma unroll
  for (int off = 1; off < 64; off <<= 1) {
    int u = (t >= off && t < 64) ? tmp[t - off] : 0;
    __syncthreads();
    if (t < 64) tmp[t] += u;
    __syncthreads();
  }
  if (t < 64) {
    int c8 = (cnt[t] + 7) & ~7;
    int ex = tmp[t] - c8;
    cur[t] = ex;
    int nd = node0 + t;
    if (nd < n) {
      row_start[nd] = (b << BSHIFT) + ex;
      row_cnt[nd] = cnt[t];
    }
  }
  __syncthreads();
  for (int i = t; i < len; i += 512) {
    int p = eb[i];
    int sub = atomicAdd(&cur[p & 63], 1);
    int s = p >> 6;
    if (sub < BCAP) { gsrc[sub] = s; reg[sub] = s; }   // LDS + global copies
  }
  __syncthreads();
  if (t < 64) {                       // pad tail of each list with sentinel n
    int c8 = (cnt[t] + 7) & ~7;
    int e1 = tmp[t];
    for (int j = e1 - c8 + cnt[t]; j < e1; ++j)
      if (j < BCAP) { gsrc[j] = n; reg[j] = n; }
  }
  __syncthreads();

  // --- fp8 agg64: 8 waves, 2 nodes each, 2-deep prefetch (16 edges/node in flight) ---
  const int lane = t & 63;
  const int wv = t >> 6;
  const int eq = lane >> 3;            // edge slot 0..7
  const int cl = lane & 7;             // 8-B chunk: cols cl*8..cl*8+7
#pragma unroll 1
  for (int p = 0; p < 4; ++p) {
    int locA = wv + p * 16;
    int locB = locA + 8;
    int cnA = cnt[locA], cnB = cnt[locB];
    int cpA = (cnA + 7) & ~7, cpB = (cnB + 7) & ~7;
    int baseA = tmp[locA] - cpA;
    int baseB = tmp[locB] - cpB;
    floatx2 aA[4], aB[4];
#pragma unroll
    for (int j = 0; j < 4; ++j) { aA[j] = (floatx2){0.f, 0.f}; aB[j] = (floatx2){0.f, 0.f}; }
    int mx = max(cpA, cpB);
    int sA = (0 < cpA) ? gsrc[baseA + eq] : n;
    int sB = (0 < cpB) ? gsrc[baseB + eq] : n;
    int sA1 = (8 < cpA) ? gsrc[baseA + 8 + eq] : n;
    int sB1 = (8 < cpB) ? gsrc[baseB + 8 + eq] : n;
    intx2 vA = *(const intx2*)(xq + (size_t)sA * 64 + cl * 8);
    intx2 vB = *(const intx2*)(xq + (size_t)sB * 64 + cl * 8);
    intx2 uA = *(const intx2*)(xq + (size_t)sA1 * 64 + cl * 8);
    intx2 uB = *(const intx2*)(xq + (size_t)sB1 * 64 + cl * 8);
    for (int e = 16; e < mx; e += 8) {
      int nA = (e < cpA) ? gsrc[baseA + e + eq] : n;
      int nB = (e < cpB) ? gsrc[baseB + e + eq] : n;
      intx2 wA = *(const intx2*)(xq + (size_t)nA * 64 + cl * 8);
      intx2 wB = *(const intx2*)(xq + (size_t)nB * 64 + cl * 8);
      fp8x8_acc(vA, aA);
      fp8x8_acc(vB, aB);
      vA = uA; vB = uB; uA = wA; uB = wB;
    }
    fp8x8_acc(vA, aA);
    fp8x8_acc(vB, aB);
    fp8x8_acc(uA, aA);
    fp8x8_acc(uB, aB);
    float rA[8], rB[8];
#pragma unroll
    for (int j = 0; j < 4; ++j) {
      rA[2 * j] = aA[j][0]; rA[2 * j + 1] = aA[j][1];
      rB[2 * j] = aB[j][0]; rB[2 * j + 1] = aB[j][1];
    }
#pragma unroll
    for (int j = 0; j < 8; ++j) {
      rA[j] += __shfl_xor(rA[j], 8, 64);
      rA[j] += __shfl_xor(rA[j], 16, 64);
      rA[j] += __shfl_xor(rA[j], 32, 64);
      rB[j] += __shfl_xor(rB[j], 8, 64);
      rB[j] += __shfl_xor(rB[j], 16, 64);
      rB[j] += __shfl_xor(rB[j], 32, 64);
    }
    if (eq == 0) {
      float invA = 1.0f / (float)max(cnA, 1);
      float invB = 1.0f / (float)max(cnB, 1);
      short8 oA, oB;
#pragma unroll
      for (int j = 0; j < 8; ++j) { oA[j] = (short)f2bf(rA[j] * invA); oB[j] = (short)f2bf(rB[j] * invB); }
      *(short8*)(aggS + locA * 72 + cl * 8) = oA;
      *(short8*)(aggS + locB * 72 + cl * 8) = oB;
    }
  }
  __syncthreads();

  // --- MFMA gemm1: 8 waves = 2 row-tiles x 4 col-tiles of 32x32; K=128 ---
  const int m = lane & 15;
  const int q = lane >> 4;
  const int rw = (wv & 1) * 32;
  const int cw = (wv >> 1) * 32;
  floatx4 acc[2][2];
#pragma unroll
  for (int rt = 0; rt < 2; ++rt)
#pragma unroll
    for (int ct = 0; ct < 2; ++ct) acc[rt][ct] = (floatx4){0.f, 0.f, 0.f, 0.f};

  int ra = node0 + rw + m;      if (ra > n - 1) ra = n - 1;
  int rb = node0 + rw + 16 + m; if (rb > n - 1) rb = n - 1;
  const unsigned short* selfA0 = xb + (size_t)ra * 64 + q * 8;
  const unsigned short* selfA1 = xb + (size_t)rb * 64 + q * 8;
  const unsigned short* aggL0 = aggS + (rw + m) * 72 + q * 8;
  const unsigned short* aggL1 = aggS + (rw + 16 + m) * 72 + q * 8;
  const unsigned short* Wc0 = W1 + (size_t)(cw + m) * 128 + q * 8;
  const unsigned short* Wc1 = W1 + (size_t)(cw + 16 + m) * 128 + q * 8;

#pragma unroll
  for (int kc = 0; kc < 2; ++kc) {     // agg half: k 0..63
    short8 a0 = *(const short8*)(aggL0 + kc * 32);
    short8 a1 = *(const short8*)(aggL1 + kc * 32);
    short8 w0 = *(const short8*)(Wc0 + kc * 32);
    short8 w1 = *(const short8*)(Wc1 + kc * 32);
    acc[0][0] = __builtin_amdgcn_mfma_f32_16x16x32_bf16(a0, w0, acc[0][0], 0, 0, 0);
    acc[0][1] = __builtin_amdgcn_mfma_f32_16x16x32_bf16(a0, w1, acc[0][1], 0, 0, 0);
    acc[1][0] = __builtin_amdgcn_mfma_f32_16x16x32_bf16(a1, w0, acc[1][0], 0, 0, 0);
    acc[1][1] = __builtin_amdgcn_mfma_f32_16x16x32_bf16(a1, w1, acc[1][1], 0, 0, 0);
  }
#pragma unroll
  for (int kc = 0; kc < 2; ++kc) {     // self half: k 64..127
    short8 a0 = *(const short8*)(selfA0 + kc * 32);
    short8 a1 = *(const short8*)(selfA1 + kc * 32);
    short8 w0 = *(const short8*)(Wc0 + 64 + kc * 32);
    short8 w1 = *(const short8*)(Wc1 + 64 + kc * 32);
    acc[0][0] = __builtin_amdgcn_mfma_f32_16x16x32_bf16(a0, w0, acc[0][0], 0, 0, 0);
    acc[0][1] = __builtin_amdgcn_mfma_f32_16x16x32_bf16(a0, w1, acc[0][1], 0, 0, 0);
    acc[1][0] = __builtin_amdgcn_mfma_f32_16x16x32_bf16(a1, w0, acc[1][0], 0, 0, 0);
    acc[1][1] = __builtin_amdgcn_mfma_f32_16x16x32_bf16(a1, w1, acc[1][1], 0, 0, 0);
  }

  float bv0 = b1[cw + m], bv1 = b1[cw + 16 + m];
#pragma unroll
  for (int rt = 0; rt < 2; ++rt) {
#pragma unroll
    for (int j = 0; j < 4; ++j) {
      int row = node0 + rw + rt * 16 + q * 4 + j;
      if (row < n) {
        float v0 = acc[rt][0][j] + bv0; v0 = v0 > 0.f ? v0 : 0.f;
        float v1 = acc[rt][1][j] + bv1; v1 = v1 > 0.f ? v1 : 0.f;
        h1[(size_t)row * 128 + cw + m] = f2bf(v0);
        h1[(size_t)row * 128 + cw + 16 + m] = f2bf(v1);
        h1q[(size_t)row * 128 + cw + m] =
            (unsigned char)__builtin_amdgcn_cvt_pk_fp8_f32(v0, v0, 0, false);
        h1q[(size_t)row * 128 + cw + 16 + m] =
            (unsigned char)__builtin_amdgcn_cvt_pk_fp8_f32(v1, v1, 0, false);
      }
    }
  }
}

// ---------------- K3: fp8 agg128 (LDS metadata + 2-deep prefetch) + layer-2 MFMA GEMM ----------------

__global__ void __launch_bounds__(512, 6) agg_gemm2(
    const unsigned short* __restrict__ h1, const unsigned char* __restrict__ h1q,
    const int* __restrict__ row_start, const int* __restrict__ row_cnt,
    const int* __restrict__ buf, const unsigned short* __restrict__ W2,
    const float* __restrict__ b2, float* __restrict__ out, int n) {
  __shared__ int gsrcS[BCAP];                             // 8 KB staged indices
  __shared__ __align__(16) unsigned short aggS[64 * 136]; // 17 KB (pad 128->136)
  __shared__ int cntS[64];
  __shared__ int stS[64];
  const int t = threadIdx.x;
  const int lane = t & 63;
  const int wv = t >> 6;
  const int node0 = blockIdx.x << 6;
  const int boff = blockIdx.x << BSHIFT;

  // stage the bucket's grouped (padded) src lists + per-node metadata
  {
    const int4* b4 = (const int4*)(buf + ((size_t)blockIdx.x << BSHIFT));
    ((int4*)gsrcS)[t] = b4[t];
  }
  if (t < 64) {
    int nd = node0 + t;
    cntS[t] = (nd < n) ? row_cnt[nd] : 0;
    stS[t]  = (nd < n) ? (row_start[nd] - boff) : 0;
  }
  __syncthreads();

  // --- fp8 agg128: 8 waves; 2 nodes/wave; 2-deep prefetch (16 edges/node in flight) ---
  const int eq = lane >> 4;            // edge slot 0..3
  const int cl = lane & 15;            // 8-B chunk: cols cl*8..cl*8+7
#pragma unroll 1
  for (int lp = 0; lp < 4; ++lp) {
    int locA = wv + lp * 16;
    int locB = locA + 8;
    int cnA = cntS[locA], stA = stS[locA];
    int cnB = cntS[locB], stB = stS[locB];
    int cpA = (cnA + 7) & ~7, cpB = (cnB + 7) & ~7;
    int mx = max(cpA, cpB);
    floatx2 aA[4], aB[4];
#pragma unroll
    for (int j = 0; j < 4; ++j) { aA[j] = (floatx2){0.f, 0.f}; aB[j] = (floatx2){0.f, 0.f}; }
    // prologue: 2 steps = 16 edges per node in flight (8 wave-loads)
    int iA0 = (0 < cpA) ? gsrcS[stA + eq] : n;
    int iA1 = (0 < cpA) ? gsrcS[stA + 4 + eq] : n;
    int iB0 = (0 < cpB) ? gsrcS[stB + eq] : n;
    int iB1 = (0 < cpB) ? gsrcS[stB + 4 + eq] : n;
    intx2 vA0 = *(const intx2*)(h1q + (size_t)iA0 * 128 + cl * 8);
    intx2 vA1 = *(const intx2*)(h1q + (size_t)iA1 * 128 + cl * 8);
    intx2 vB0 = *(const intx2*)(h1q + (size_t)iB0 * 128 + cl * 8);
    intx2 vB1 = *(const intx2*)(h1q + (size_t)iB1 * 128 + cl * 8);
    int jA0 = (8 < cpA) ? gsrcS[stA + 8 + eq] : n;
    int jA1 = (8 < cpA) ? gsrcS[stA + 12 + eq] : n;
    int jB0 = (8 < cpB) ? gsrcS[stB + 8 + eq] : n;
    int jB1 = (8 < cpB) ? gsrcS[stB + 12 + eq] : n;
    intx2 uA0 = *(const intx2*)(h1q + (size_t)jA0 * 128 + cl * 8);
    intx2 uA1 = *(const intx2*)(h1q + (size_t)jA1 * 128 + cl * 8);
    intx2 uB0 = *(const intx2*)(h1q + (size_t)jB0 * 128 + cl * 8);
    intx2 uB1 = *(const intx2*)(h1q + (size_t)jB1 * 128 + cl * 8);
    for (int e = 16; e < mx; e += 8) {
      int kA0 = (e < cpA) ? gsrcS[stA + e + eq] : n;
      int kA1 = (e < cpA) ? gsrcS[stA + e + 4 + eq] : n;
      int kB0 = (e < cpB) ? gsrcS[stB + e + eq] : n;
      int kB1 = (e < cpB) ? gsrcS[stB + e + 4 + eq] : n;
      intx2 wA0 = *(const intx2*)(h1q + (size_t)kA0 * 128 + cl * 8);
      intx2 wA1 = *(const intx2*)(h1q + (size_t)kA1 * 128 + cl * 8);
      intx2 wB0 = *(const intx2*)(h1q + (size_t)kB0 * 128 + cl * 8);
      intx2 wB1 = *(const intx2*)(h1q + (size_t)kB1 * 128 + cl * 8);
      fp8x8_acc(vA0, aA); fp8x8_acc(vA1, aA);
      fp8x8_acc(vB0, aB); fp8x8_acc(vB1, aB);
      vA0 = uA0; vA1 = uA1; vB0 = uB0; vB1 = uB1;
      uA0 = wA0; uA1 = wA1; uB0 = wB0; uB1 = wB1;
    }
    fp8x8_acc(vA0, aA); fp8x8_acc(vA1, aA);
    fp8x8_acc(vB0, aB); fp8x8_acc(vB1, aB);
    fp8x8_acc(uA0, aA); fp8x8_acc(uA1, aA);
    fp8x8_acc(uB0, aB); fp8x8_acc(uB1, aB);

    float rA[8], rB[8];
#pragma unroll
    for (int j = 0; j < 4; ++j) {
      rA[2 * j] = aA[j][0]; rA[2 * j + 1] = aA[j][1];
      rB[2 * j] = aB[j][0]; rB[2 * j + 1] = aB[j][1];
    }
#pragma unroll
    for (int j = 0; j < 8; ++j) {
      rA[j] += __shfl_xor(rA[j], 16, 64);
      rA[j] += __shfl_xor(rA[j], 32, 64);
      rB[j] += __shfl_xor(rB[j], 16, 64);
      rB[j] += __shfl_xor(rB[j], 32, 64);
    }
    if (eq == 0) {
      float invA = 1.0f / (float)max(cnA, 1);
      float invB = 1.0f / (float)max(cnB, 1);
      short8 oA, oB;
#pragma unroll
      for (int j = 0; j < 8; ++j) { oA[j] = (short)f2bf(rA[j] * invA); oB[j] = (short)f2bf(rB[j] * invB); }
      *(short8*)(aggS + locA * 136 + cl * 8) = oA;
      *(short8*)(aggS + locB * 136 + cl * 8) = oB;
    }
  }
  __syncthreads();

  // --- MFMA gemm2: 8 waves = 2 row-tiles x 4 col-tiles of 32x32; K=256 ---
  const int m = lane & 15;
  const int q = lane >> 4;
  const int rw = (wv & 1) * 32;
  const int cw = (wv >> 1) * 32;
  floatx4 acc[2][2];
#pragma unroll
  for (int rt = 0; rt < 2; ++rt)
#pragma unroll
    for (int ct = 0; ct < 2; ++ct) acc[rt][ct] = (floatx4){0.f, 0.f, 0.f, 0.f};

  int ra = node0 + rw + m;      if (ra > n - 1) ra = n - 1;
  int rb = node0 + rw + 16 + m; if (rb > n - 1) rb = n - 1;
  const unsigned short* selfA0 = h1 + (size_t)ra * 128 + q * 8;
  const unsigned short* selfA1 = h1 + (size_t)rb * 128 + q * 8;
  const unsigned short* aggL0 = aggS + (rw + m) * 136 + q * 8;
  const unsigned short* aggL1 = aggS + (rw + 16 + m) * 136 + q * 8;
  const unsigned short* Wc0 = W2 + (size_t)(cw + m) * 256 + q * 8;
  const unsigned short* Wc1 = W2 + (size_t)(cw + 16 + m) * 256 + q * 8;

#pragma unroll
  for (int kc = 0; kc < 4; ++kc) {     // agg half: k 0..127
    short8 a0 = *(const short8*)(aggL0 + kc * 32);
    short8 a1 = *(const short8*)(aggL1 + kc * 32);
    short8 w0 = *(const short8*)(Wc0 + kc * 32);
    short8 w1 = *(const short8*)(Wc1 + kc * 32);
    acc[0][0] = __builtin_amdgcn_mfma_f32_16x16x32_bf16(a0, w0, acc[0][0], 0, 0, 0);
    acc[0][1] = __builtin_amdgcn_mfma_f32_16x16x32_bf16(a0, w1, acc[0][1], 0, 0, 0);
    acc[1][0] = __builtin_amdgcn_mfma_f32_16x16x32_bf16(a1, w0, acc[1][0], 0, 0, 0);
    acc[1][1] = __builtin_amdgcn_mfma_f32_16x16x32_bf16(a1, w1, acc[1][1], 0, 0, 0);
  }
#pragma unroll
  for (int kc = 0; kc < 4; ++kc) {     // self half: k 128..255
    short8 a0 = *(const short8*)(selfA0 + kc * 32);
    short8 a1 = *(const short8*)(selfA1 + kc * 32);
    short8 w0 = *(const short8*)(Wc0 + 128 + kc * 32);
    short8 w1 = *(const short8*)(Wc1 + 128 + kc * 32);
    acc[0][0] = __builtin_amdgcn_mfma_f32_16x16x32_bf16(a0, w0, acc[0][0], 0, 0, 0);
    acc[0][1] = __builtin_amdgcn_mfma_f32_16x16x32_bf16(a0, w1, acc[0][1], 0, 0, 0);
    acc[1][0] = __builtin_amdgcn_mfma_f32_16x16x32_bf16(a1, w0, acc[1][0], 0, 0, 0);
    acc[1][1] = __builtin_amdgcn_mfma_f32_16x16x32_bf16(a1, w1, acc[1][1], 0, 0, 0);
  }

  float bv0 = b2[cw + m], bv1 = b2[cw + 16 + m];
#pragma unroll
  for (int rt = 0; rt < 2; ++rt) {
#pragma unroll
    for (int j = 0; j < 4; ++j) {
      int row = node0 + rw + rt * 16 + q * 4 + j;
      if (row < n) {
        float v0 = acc[rt][0][j] + bv0; v0 = v0 > 0.f ? v0 : 0.f;
        float v1 = acc[rt][1][j] + bv1; v1 = v1 > 0.f ? v1 : 0.f;
        out[(size_t)row * 128 + cw + m] = v0;
        out[(size_t)row * 128 + cw + 16 + m] = v1;
      }
    }
  }
}

// ---------------- launch ----------------

extern "C" void kernel_launch(void* const* d_in, const int* in_sizes, int n_in,
                              void* d_out, int out_size, void* d_ws, size_t ws_size,
                              hipStream_t stream) {
  const int N = N_NODES;
  const int E = in_sizes[1] / 2;
  const float* x   = (const float*)d_in[0];
  const int*   src = (const int*)d_in[1];
  const int*   dst = src + E;
  const float* Wl1 = (const float*)d_in[2];
  const float* Wr1 = (const float*)d_in[3];
  const float* b1  = (const float*)d_in[4];
  const float* Wl2 = (const float*)d_in[5];
  const float* Wr2 = (const float*)d_in[6];
  const float* b2  = (const float*)d_in[7];
  float* out = (float*)d_out;

  // workspace (~36 MB)
  unsigned short* xb = (unsigned short*)d_ws;         // N*64 bf16 (x cast)
  unsigned short* h1 = xb + (size_t)N * 64;           // N*128 bf16 (layer-1 out)
  unsigned short* W1 = h1 + (size_t)N * 128;          // 128*128
  unsigned short* W2 = W1 + 128 * 128;                // 128*256
  int* row_start  = (int*)(W2 + 128 * 256);           // N
  int* row_cnt    = row_start + N;                    // N
  int* bucket_cur = row_cnt + N;                      // NBUCK (padded to 784)
  int* buf        = bucket_cur + 784;                 // NBUCK*BCAP ints (6.4 MB)
  unsigned char* xq  = (unsigned char*)(buf + (size_t)NBUCK * BCAP);  // (N+1)*64 fp8
  unsigned char* h1q = xq + ((size_t)N + 1) * 64;                     // (N+1)*128 fp8

  (void)hipMemsetAsync(bucket_cur, 0, NBUCK * sizeof(int), stream);
  int sb = (E + 4095) / 4096;                         // 196 blocks
  prep_scatter<<<sb, 512, 0, stream>>>(x, Wl1, Wr1, Wl2, Wr2, xb, xq, W1, W2,
                                       src, dst, bucket_cur, buf, E, N);
  csr_agg_gemm1<<<NBUCK, 512, 0, stream>>>(buf, bucket_cur, row_start, row_cnt,
                                           xb, xq, W1, b1, h1, h1q, N);
  agg_gemm2<<<NBUCK, 512, 0, stream>>>(h1, h1q, row_start, row_cnt, buf, W2, b2, out, N);
}